// Round 1
// baseline (773.017 us; speedup 1.0000x reference)
//
#include <hip/hip_runtime.h>
#include <float.h>

#define K_NN 10
#define BATCH 8
#define CIN 6
#define NPTS 4096
#define COUT 64
#define NEG_SLOPE 0.2f
#define BN_EPS 1e-5f

// ---- workspace layout (bytes) ----
static constexpr size_t OFF_IDX = 0;                                                   // int[8*4096*10]
static constexpr size_t OFF_PTS = OFF_IDX + (size_t)BATCH * NPTS * K_NN * sizeof(int); // float4[8*4096]
static constexpr size_t OFF_Q   = OFF_PTS + (size_t)BATCH * NPTS * sizeof(float4);     // float[8*64*4096]
static constexpr size_t OFF_ST  = OFF_Q + (size_t)BATCH * COUT * NPTS * sizeof(float); // double[27]
static constexpr size_t OFF_SS  = OFF_ST + 32 * sizeof(double);                        // float[128] scale/shift
// total ~10.23 MB

__device__ __forceinline__ float wave_sum(float v) {
#pragma unroll
    for (int m = 32; m >= 1; m >>= 1) v += __shfl_xor(v, m, 64);
    return v;
}
__device__ __forceinline__ float wave_max(float v) {
#pragma unroll
    for (int m = 32; m >= 1; m >>= 1) v = fmaxf(v, __shfl_xor(v, m, 64));
    return v;
}

// ---- Kernel P: pack (x,y,z,||p||^2) per point ----
__global__ __launch_bounds__(256) void prep_pts(const float* __restrict__ x,
                                                float4* __restrict__ pts) {
    int t = blockIdx.x * 256 + threadIdx.x;   // 0..32767
    int b = t >> 12;
    int n = t & (NPTS - 1);
    const float* xb = x + (size_t)b * CIN * NPTS;
    float x0 = xb[n];
    float x1 = xb[NPTS + n];
    float x2 = xb[2 * NPTS + n];
    pts[t] = make_float4(x0, x1, x2, x0 * x0 + x1 * x1 + x2 * x2);
}

// ---- Kernel A: exact top-10 NN per point (largest pd = 2*inner - xx_n - xx_m) ----
__global__ __launch_bounds__(256) void knn_kernel(const float4* __restrict__ pts,
                                                  int* __restrict__ idxo) {
    int b = blockIdx.y;
    int n = blockIdx.x * 256 + threadIdx.x;
    const float4* p = pts + (size_t)b * NPTS;   // wave-uniform base
    float4 qp = p[n];

    float vals[K_NN];
    int inds[K_NN];
#pragma unroll
    for (int j = 0; j < K_NN; j++) { vals[j] = -FLT_MAX; inds[j] = 0; }

#pragma unroll 4
    for (int m = 0; m < NPTS; m++) {
        float4 c = p[m];                         // uniform -> scalar load path
        float inner = qp.x * c.x + qp.y * c.y + qp.z * c.z;
        float d = 2.0f * inner - qp.w - c.w;
        if (d > vals[K_NN - 1]) {                // strict > : keeps earliest index on ties
            vals[K_NN - 1] = d;
            inds[K_NN - 1] = m;
#pragma unroll
            for (int j = K_NN - 1; j > 0; j--) { // one bubble pass restores sorted order
                if (vals[j] > vals[j - 1]) {
                    float tv = vals[j]; vals[j] = vals[j - 1]; vals[j - 1] = tv;
                    int ti = inds[j]; inds[j] = inds[j - 1]; inds[j - 1] = ti;
                }
            }
        }
    }

    int* o = idxo + ((size_t)b * NPTS + n) * K_NN;
#pragma unroll
    for (int j = 0; j < K_NN; j++) o[j] = inds[j];
}

// ---- Kernel B: gather + center + q[b,o,n] = max_k (W feat)  + moment stats ----
__global__ __launch_bounds__(256) void feat_kernel(const float* __restrict__ x,
                                                   const float* __restrict__ W,
                                                   const int* __restrict__ idx,
                                                   float* __restrict__ q,
                                                   double* __restrict__ stats) {
    __shared__ float sW[COUT * CIN];
    __shared__ float sred[4][27];
    for (int i = threadIdx.x; i < COUT * CIN; i += 256) sW[i] = W[i];
    __syncthreads();

    int b = blockIdx.y;
    int n = blockIdx.x * 256 + threadIdx.x;
    const float* xb = x + (size_t)b * CIN * NPTS;
    const int* id = idx + ((size_t)b * NPTS + n) * K_NN;

    int nb[K_NN];
#pragma unroll
    for (int k = 0; k < K_NN; k++) nb[k] = id[k];

    float f[CIN][K_NN];
#pragma unroll
    for (int c = 0; c < CIN; c++)
#pragma unroll
        for (int k = 0; k < K_NN; k++)
            f[c][k] = xb[c * NPTS + nb[k]];

    // center xyz over k, scale by 10 (matches reference: (xyz - mean)*10)
#pragma unroll
    for (int c = 0; c < 3; c++) {
        float s = 0.f;
#pragma unroll
        for (int k = 0; k < K_NN; k++) s += f[c][k];
        float m = s / 10.0f;
#pragma unroll
        for (int k = 0; k < K_NN; k++) f[c][k] = (f[c][k] - m) * 10.0f;
    }

    // moment stats: S1[6], S2[21] (upper triangle)
    float s1[CIN];
#pragma unroll
    for (int c = 0; c < CIN; c++) {
        float s = 0.f;
#pragma unroll
        for (int k = 0; k < K_NN; k++) s += f[c][k];
        s1[c] = s;
    }
    float s2[21];
#pragma unroll
    for (int i = 0; i < 21; i++) s2[i] = 0.f;
#pragma unroll
    for (int k = 0; k < K_NN; k++) {
        int p = 0;
#pragma unroll
        for (int c = 0; c < CIN; c++)
#pragma unroll
            for (int c2 = c; c2 < CIN; c2++) {
                s2[p] += f[c][k] * f[c2][k];
                p++;
            }
    }

    // q[b,o,n] = max_k y (pre-BN; BN affine + leaky are monotone, applied later)
    float* qb = q + (size_t)b * COUT * NPTS + n;
#pragma unroll
    for (int o = 0; o < COUT; o++) {
        float w0 = sW[o * 6 + 0], w1 = sW[o * 6 + 1], w2 = sW[o * 6 + 2];
        float w3 = sW[o * 6 + 3], w4 = sW[o * 6 + 4], w5 = sW[o * 6 + 5];
        float mx = -FLT_MAX;
#pragma unroll
        for (int k = 0; k < K_NN; k++) {
            float y = w0 * f[0][k] + w1 * f[1][k] + w2 * f[2][k] +
                      w3 * f[3][k] + w4 * f[4][k] + w5 * f[5][k];
            mx = fmaxf(mx, y);
        }
        qb[(size_t)o * NPTS] = mx;
    }

    // block-level reduction of the 27 stats, then one f64 atomic per value per block
#pragma unroll
    for (int c = 0; c < CIN; c++) s1[c] = wave_sum(s1[c]);
#pragma unroll
    for (int i = 0; i < 21; i++) s2[i] = wave_sum(s2[i]);

    int wv = threadIdx.x >> 6;
    int ln = threadIdx.x & 63;
    if (ln == 0) {
#pragma unroll
        for (int c = 0; c < CIN; c++) sred[wv][c] = s1[c];
#pragma unroll
        for (int i = 0; i < 21; i++) sred[wv][6 + i] = s2[i];
    }
    __syncthreads();
    if (threadIdx.x < 27) {
        float t = sred[0][threadIdx.x] + sred[1][threadIdx.x] +
                  sred[2][threadIdx.x] + sred[3][threadIdx.x];
        atomicAdd(&stats[threadIdx.x], (double)t);
    }
}

// ---- Kernel B2: fold moments through W -> per-channel scale/shift ----
__global__ void stats_kernel(const double* __restrict__ stats,
                             const float* __restrict__ W,
                             const float* __restrict__ gamma,
                             const float* __restrict__ beta,
                             float* __restrict__ ss) {
    int o = threadIdx.x;  // 64 threads
    const double minv = 1.0 / (double)((size_t)BATCH * NPTS * K_NN);
    double w[CIN];
#pragma unroll
    for (int c = 0; c < CIN; c++) w[c] = (double)W[o * CIN + c];
    double mu = 0.0;
#pragma unroll
    for (int c = 0; c < CIN; c++) mu += w[c] * stats[c];
    mu *= minv;
    double ey2 = 0.0;
    int p = 6;
#pragma unroll
    for (int c = 0; c < CIN; c++)
#pragma unroll
        for (int c2 = c; c2 < CIN; c2++) {
            double v = w[c] * w[c2] * stats[p];
            ey2 += (c2 == c) ? v : 2.0 * v;
            p++;
        }
    ey2 *= minv;
    double var = ey2 - mu * mu;
    float scale = gamma[o] * rsqrtf((float)var + BN_EPS);
    float shift = beta[o] - (float)mu * scale;
    ss[o] = scale;
    ss[COUT + o] = shift;
}

// ---- Kernel C: z = leaky(scale*q+shift); reduce max & mean over n ----
__global__ __launch_bounds__(256) void reduce_kernel(const float* __restrict__ q,
                                                     const float* __restrict__ ss,
                                                     float* __restrict__ out) {
    int o = blockIdx.x;
    int b = blockIdx.y;
    const float* qp = q + ((size_t)b * COUT + o) * NPTS;
    float scale = ss[o], shift = ss[COUT + o];
    float mx = -FLT_MAX, sm = 0.f;
    for (int i = threadIdx.x; i < NPTS; i += 256) {
        float z = scale * qp[i] + shift;
        z = (z >= 0.f) ? z : NEG_SLOPE * z;
        mx = fmaxf(mx, z);
        sm += z;
    }
    mx = wave_max(mx);
    sm = wave_sum(sm);
    __shared__ float smx[4], ssm[4];
    int wv = threadIdx.x >> 6;
    int ln = threadIdx.x & 63;
    if (ln == 0) { smx[wv] = mx; ssm[wv] = sm; }
    __syncthreads();
    if (threadIdx.x == 0) {
        float m = fmaxf(fmaxf(smx[0], smx[1]), fmaxf(smx[2], smx[3]));
        float s = ssm[0] + ssm[1] + ssm[2] + ssm[3];
        out[b * 2 * COUT + o] = m;
        out[b * 2 * COUT + COUT + o] = s * (1.0f / (float)NPTS);
    }
}

extern "C" void kernel_launch(void* const* d_in, const int* in_sizes, int n_in,
                              void* d_out, int out_size, void* d_ws, size_t ws_size,
                              hipStream_t stream) {
    const float* x     = (const float*)d_in[0];
    const float* W     = (const float*)d_in[1];
    const float* gamma = (const float*)d_in[2];
    const float* beta  = (const float*)d_in[3];
    float* out = (float*)d_out;

    char* ws = (char*)d_ws;
    int*    idx   = (int*)(ws + OFF_IDX);
    float4* pts   = (float4*)(ws + OFF_PTS);
    float*  q     = (float*)(ws + OFF_Q);
    double* stats = (double*)(ws + OFF_ST);
    float*  ss    = (float*)(ws + OFF_SS);

    hipMemsetAsync(stats, 0, 27 * sizeof(double), stream);
    prep_pts<<<BATCH * NPTS / 256, 256, 0, stream>>>(x, pts);
    knn_kernel<<<dim3(NPTS / 256, BATCH), 256, 0, stream>>>(pts, idx);
    feat_kernel<<<dim3(NPTS / 256, BATCH), 256, 0, stream>>>(x, W, idx, q, stats);
    stats_kernel<<<1, COUT, 0, stream>>>(stats, W, gamma, beta, ss);
    reduce_kernel<<<dim3(COUT, BATCH), 256, 0, stream>>>(q, ss, out);
}

// Round 2
// 309.438 us; speedup vs baseline: 2.4981x; 2.4981x over previous
//
#include <hip/hip_runtime.h>
#include <float.h>

#define K_NN 10
#define BATCH 8
#define CIN 6
#define NPTS 4096
#define COUT 64
#define NSEG 8
#define SEGLEN (NPTS / NSEG)   // 512
#define NEG_SLOPE 0.2f
#define BN_EPS 1e-5f

// ---- workspace layout (bytes) ----
// part[] (segment top-10 indices) aliases q[] : part is consumed by merge_kernel
// before feat_kernel writes q. part = 10.49 MB > q = 8.39 MB, so region is 10.49 MB.
static constexpr size_t OFF_IDX = 0;                                                   // int[8*4096*10]
static constexpr size_t OFF_PTS = OFF_IDX + (size_t)BATCH * NPTS * K_NN * sizeof(int); // float4[8*4096]
static constexpr size_t OFF_Q   = OFF_PTS + (size_t)BATCH * NPTS * sizeof(float4);     // alias: q / part
static constexpr size_t SZ_Q    = (size_t)NSEG * BATCH * NPTS * K_NN * sizeof(int);    // 10.49 MB
static constexpr size_t OFF_ST  = OFF_Q + SZ_Q;                                        // double[27]
static constexpr size_t OFF_SS  = OFF_ST + 32 * sizeof(double);                        // float[128]

__device__ __forceinline__ float wave_sum(float v) {
#pragma unroll
    for (int m = 32; m >= 1; m >>= 1) v += __shfl_xor(v, m, 64);
    return v;
}
__device__ __forceinline__ float wave_max(float v) {
#pragma unroll
    for (int m = 32; m >= 1; m >>= 1) v = fmaxf(v, __shfl_xor(v, m, 64));
    return v;
}

// ---- Kernel P: pack (x,y,z,||p||^2) per point ----
__global__ __launch_bounds__(256) void prep_pts(const float* __restrict__ x,
                                                float4* __restrict__ pts) {
    int t = blockIdx.x * 256 + threadIdx.x;   // 0..32767
    int b = t >> 12;
    int n = t & (NPTS - 1);
    const float* xb = x + (size_t)b * CIN * NPTS;
    float x0 = xb[n];
    float x1 = xb[NPTS + n];
    float x2 = xb[2 * NPTS + n];
    pts[t] = make_float4(x0, x1, x2, x0 * x0 + x1 * x1 + x2 * x2);
}

// ---- Kernel A1: per-segment top-10 (candidates [s*512,(s+1)*512) ) ----
__global__ __launch_bounds__(256) void knn_part(const float4* __restrict__ pts,
                                                int* __restrict__ part) {
    int b = blockIdx.y;
    int s = blockIdx.z;
    int n = blockIdx.x * 256 + threadIdx.x;
    const float4* p = pts + (size_t)b * NPTS;   // wave-uniform base
    float4 qp = p[n];

    float vals[K_NN];
    int inds[K_NN];
#pragma unroll
    for (int j = 0; j < K_NN; j++) { vals[j] = -FLT_MAX; inds[j] = 0; }

    int m0 = s * SEGLEN;
#pragma unroll 8
    for (int mm = 0; mm < SEGLEN; mm++) {
        int m = m0 + mm;
        float4 c = p[m];                         // uniform -> scalar load path
        float inner = qp.x * c.x + qp.y * c.y + qp.z * c.z;
        float d = 2.0f * inner - qp.w - c.w;
        if (d > vals[K_NN - 1]) {
            vals[K_NN - 1] = d;
            inds[K_NN - 1] = m;
#pragma unroll
            for (int j = K_NN - 1; j > 0; j--) {
                if (vals[j] > vals[j - 1]) {
                    float tv = vals[j]; vals[j] = vals[j - 1]; vals[j - 1] = tv;
                    int ti = inds[j]; inds[j] = inds[j - 1]; inds[j - 1] = ti;
                }
            }
        }
    }

    // coalesced layout: part[(((s*B+b)*10 + j)*NPTS + n]
    int* o = part + (((size_t)s * BATCH + b) * K_NN) * NPTS + n;
#pragma unroll
    for (int j = 0; j < K_NN; j++) o[(size_t)j * NPTS] = inds[j];
}

// ---- Kernel A2: merge 8 segment lists -> global top-10 (re-evaluates 80 cands) ----
__global__ __launch_bounds__(256) void merge_kernel(const float4* __restrict__ pts,
                                                    const int* __restrict__ part,
                                                    int* __restrict__ idxo) {
    int b = blockIdx.y;
    int n = blockIdx.x * 256 + threadIdx.x;
    const float4* p = pts + (size_t)b * NPTS;
    float4 qp = p[n];

    float vals[K_NN];
    int inds[K_NN];
#pragma unroll
    for (int j = 0; j < K_NN; j++) { vals[j] = -FLT_MAX; inds[j] = 0; }

#pragma unroll
    for (int s = 0; s < NSEG; s++) {
        const int* pp = part + (((size_t)s * BATCH + b) * K_NN) * NPTS + n;
#pragma unroll
        for (int j = 0; j < K_NN; j++) {
            int m = pp[(size_t)j * NPTS];
            float4 c = p[m];                     // divergent but L1/L2-resident (512 KB)
            float inner = qp.x * c.x + qp.y * c.y + qp.z * c.z;
            float d = 2.0f * inner - qp.w - c.w;
            if (d > vals[K_NN - 1]) {
                vals[K_NN - 1] = d;
                inds[K_NN - 1] = m;
#pragma unroll
                for (int t = K_NN - 1; t > 0; t--) {
                    if (vals[t] > vals[t - 1]) {
                        float tv = vals[t]; vals[t] = vals[t - 1]; vals[t - 1] = tv;
                        int ti = inds[t]; inds[t] = inds[t - 1]; inds[t - 1] = ti;
                    }
                }
            }
        }
    }

    int* o = idxo + ((size_t)b * NPTS + n) * K_NN;
#pragma unroll
    for (int j = 0; j < K_NN; j++) o[j] = inds[j];
}

// ---- Kernel B: gather + center + q[b,o,n] = max_k (W feat)  + moment stats ----
// blockIdx.z selects a group of 16 output channels; group 0 also does stats.
__global__ __launch_bounds__(256) void feat_kernel(const float* __restrict__ x,
                                                   const float* __restrict__ W,
                                                   const int* __restrict__ idx,
                                                   float* __restrict__ q,
                                                   double* __restrict__ stats) {
    __shared__ float sW[COUT * CIN];
    __shared__ float sred[4][27];
    for (int i = threadIdx.x; i < COUT * CIN; i += 256) sW[i] = W[i];
    __syncthreads();

    int b = blockIdx.y;
    int g = blockIdx.z;           // o in [g*16, g*16+16)
    int n = blockIdx.x * 256 + threadIdx.x;
    const float* xb = x + (size_t)b * CIN * NPTS;
    const int* id = idx + ((size_t)b * NPTS + n) * K_NN;

    int nb[K_NN];
#pragma unroll
    for (int k = 0; k < K_NN; k++) nb[k] = id[k];

    float f[CIN][K_NN];
#pragma unroll
    for (int c = 0; c < CIN; c++)
#pragma unroll
        for (int k = 0; k < K_NN; k++)
            f[c][k] = xb[c * NPTS + nb[k]];

    // center xyz over k, scale by 10
#pragma unroll
    for (int c = 0; c < 3; c++) {
        float s = 0.f;
#pragma unroll
        for (int k = 0; k < K_NN; k++) s += f[c][k];
        float m = s / 10.0f;
#pragma unroll
        for (int k = 0; k < K_NN; k++) f[c][k] = (f[c][k] - m) * 10.0f;
    }

    // q[b,o,n] = max_k y for this group's 16 channels
    float* qb = q + (size_t)b * COUT * NPTS + n;
#pragma unroll
    for (int oo = 0; oo < 16; oo++) {
        int o = g * 16 + oo;
        float w0 = sW[o * 6 + 0], w1 = sW[o * 6 + 1], w2 = sW[o * 6 + 2];
        float w3 = sW[o * 6 + 3], w4 = sW[o * 6 + 4], w5 = sW[o * 6 + 5];
        float mx = -FLT_MAX;
#pragma unroll
        for (int k = 0; k < K_NN; k++) {
            float y = w0 * f[0][k] + w1 * f[1][k] + w2 * f[2][k] +
                      w3 * f[3][k] + w4 * f[4][k] + w5 * f[5][k];
            mx = fmaxf(mx, y);
        }
        qb[(size_t)o * NPTS] = mx;
    }

    if (g != 0) return;

    // moment stats: S1[6], S2[21]
    float s1[CIN];
#pragma unroll
    for (int c = 0; c < CIN; c++) {
        float s = 0.f;
#pragma unroll
        for (int k = 0; k < K_NN; k++) s += f[c][k];
        s1[c] = s;
    }
    float s2[21];
#pragma unroll
    for (int i = 0; i < 21; i++) s2[i] = 0.f;
#pragma unroll
    for (int k = 0; k < K_NN; k++) {
        int p = 0;
#pragma unroll
        for (int c = 0; c < CIN; c++)
#pragma unroll
            for (int c2 = c; c2 < CIN; c2++) {
                s2[p] += f[c][k] * f[c2][k];
                p++;
            }
    }
#pragma unroll
    for (int c = 0; c < CIN; c++) s1[c] = wave_sum(s1[c]);
#pragma unroll
    for (int i = 0; i < 21; i++) s2[i] = wave_sum(s2[i]);

    int wv = threadIdx.x >> 6;
    int ln = threadIdx.x & 63;
    if (ln == 0) {
#pragma unroll
        for (int c = 0; c < CIN; c++) sred[wv][c] = s1[c];
#pragma unroll
        for (int i = 0; i < 21; i++) sred[wv][6 + i] = s2[i];
    }
    __syncthreads();
    if (threadIdx.x < 27) {
        float t = sred[0][threadIdx.x] + sred[1][threadIdx.x] +
                  sred[2][threadIdx.x] + sred[3][threadIdx.x];
        atomicAdd(&stats[threadIdx.x], (double)t);
    }
}

// ---- Kernel B2: fold moments through W -> per-channel scale/shift ----
__global__ void stats_kernel(const double* __restrict__ stats,
                             const float* __restrict__ W,
                             const float* __restrict__ gamma,
                             const float* __restrict__ beta,
                             float* __restrict__ ss) {
    int o = threadIdx.x;  // 64 threads
    const double minv = 1.0 / (double)((size_t)BATCH * NPTS * K_NN);
    double w[CIN];
#pragma unroll
    for (int c = 0; c < CIN; c++) w[c] = (double)W[o * CIN + c];
    double mu = 0.0;
#pragma unroll
    for (int c = 0; c < CIN; c++) mu += w[c] * stats[c];
    mu *= minv;
    double ey2 = 0.0;
    int p = 6;
#pragma unroll
    for (int c = 0; c < CIN; c++)
#pragma unroll
        for (int c2 = c; c2 < CIN; c2++) {
            double v = w[c] * w[c2] * stats[p];
            ey2 += (c2 == c) ? v : 2.0 * v;
            p++;
        }
    ey2 *= minv;
    double var = ey2 - mu * mu;
    float scale = gamma[o] * rsqrtf((float)var + BN_EPS);
    float shift = beta[o] - (float)mu * scale;
    ss[o] = scale;
    ss[COUT + o] = shift;
}

// ---- Kernel C: z = leaky(scale*q+shift); reduce max & mean over n ----
__global__ __launch_bounds__(256) void reduce_kernel(const float* __restrict__ q,
                                                     const float* __restrict__ ss,
                                                     float* __restrict__ out) {
    int o = blockIdx.x;
    int b = blockIdx.y;
    const float* qp = q + ((size_t)b * COUT + o) * NPTS;
    float scale = ss[o], shift = ss[COUT + o];
    float mx = -FLT_MAX, sm = 0.f;
    for (int i = threadIdx.x; i < NPTS; i += 256) {
        float z = scale * qp[i] + shift;
        z = (z >= 0.f) ? z : NEG_SLOPE * z;
        mx = fmaxf(mx, z);
        sm += z;
    }
    mx = wave_max(mx);
    sm = wave_sum(sm);
    __shared__ float smx[4], ssm[4];
    int wv = threadIdx.x >> 6;
    int ln = threadIdx.x & 63;
    if (ln == 0) { smx[wv] = mx; ssm[wv] = sm; }
    __syncthreads();
    if (threadIdx.x == 0) {
        float m = fmaxf(fmaxf(smx[0], smx[1]), fmaxf(smx[2], smx[3]));
        float s = ssm[0] + ssm[1] + ssm[2] + ssm[3];
        out[b * 2 * COUT + o] = m;
        out[b * 2 * COUT + COUT + o] = s * (1.0f / (float)NPTS);
    }
}

extern "C" void kernel_launch(void* const* d_in, const int* in_sizes, int n_in,
                              void* d_out, int out_size, void* d_ws, size_t ws_size,
                              hipStream_t stream) {
    const float* x     = (const float*)d_in[0];
    const float* W     = (const float*)d_in[1];
    const float* gamma = (const float*)d_in[2];
    const float* beta  = (const float*)d_in[3];
    float* out = (float*)d_out;

    char* ws = (char*)d_ws;
    int*    idx   = (int*)(ws + OFF_IDX);
    float4* pts   = (float4*)(ws + OFF_PTS);
    int*    part  = (int*)(ws + OFF_Q);     // aliases q region (consumed before q written)
    float*  q     = (float*)(ws + OFF_Q);
    double* stats = (double*)(ws + OFF_ST);
    float*  ss    = (float*)(ws + OFF_SS);

    hipMemsetAsync(stats, 0, 27 * sizeof(double), stream);
    prep_pts<<<BATCH * NPTS / 256, 256, 0, stream>>>(x, pts);
    knn_part<<<dim3(NPTS / 256, BATCH, NSEG), 256, 0, stream>>>(pts, part);
    merge_kernel<<<dim3(NPTS / 256, BATCH), 256, 0, stream>>>(pts, part, idx);
    feat_kernel<<<dim3(NPTS / 256, BATCH, 4), 256, 0, stream>>>(x, W, idx, q, stats);
    stats_kernel<<<1, COUT, 0, stream>>>(stats, W, gamma, beta, ss);
    reduce_kernel<<<dim3(COUT, BATCH), 256, 0, stream>>>(q, ss, out);
}

// Round 3
// 262.625 us; speedup vs baseline: 2.9434x; 1.1782x over previous
//
#include <hip/hip_runtime.h>
#include <float.h>

#define K_NN 10
#define BATCH 8
#define CIN 6
#define NPTS 4096
#define COUT 64
#define NSEG 8
#define SEGLEN (NPTS / NSEG)   // 512
#define CAP 16                 // per-lane survivor buffer (needs >= 10; ties beyond 16 are ~impossible)
#define NEG_SLOPE 0.2f
#define BN_EPS 1e-5f

// ---- workspace layout (bytes) ----
// part[] aliases q[]: part is fully consumed by merge_kernel before feat_kernel writes q.
static constexpr size_t OFF_IDX = 0;                                                   // int[8*10*4096]  (plane layout [b][j][n])
static constexpr size_t OFF_PTS = OFF_IDX + (size_t)BATCH * K_NN * NPTS * sizeof(int); // float4[8*4096]
static constexpr size_t OFF_Q   = OFF_PTS + (size_t)BATCH * NPTS * sizeof(float4);     // alias: q / part
static constexpr size_t SZ_Q    = (size_t)NSEG * BATCH * NPTS * K_NN * sizeof(int);    // 10.49 MB
static constexpr size_t OFF_ST  = OFF_Q + SZ_Q;                                        // double[27]
static constexpr size_t OFF_SS  = OFF_ST + 32 * sizeof(double);                        // float[128]

__device__ __forceinline__ float wave_sum(float v) {
#pragma unroll
    for (int m = 32; m >= 1; m >>= 1) v += __shfl_xor(v, m, 64);
    return v;
}
__device__ __forceinline__ float wave_max(float v) {
#pragma unroll
    for (int m = 32; m >= 1; m >>= 1) v = fmaxf(v, __shfl_xor(v, m, 64));
    return v;
}

// d' = 2*inner - ||c||^2  (drops per-query-constant ||q||^2: pure monotone shift,
// ordering identical; used consistently in knn_part AND merge_kernel). 4 VALU.
__device__ __forceinline__ float distp(float4 qp, float4 c) {
    return fmaf(2.0f, fmaf(qp.z, c.z, fmaf(qp.y, c.y, qp.x * c.x)), -c.w);
}

// ---- Kernel P: pack (x,y,z,||p||^2) per point; block 0 zeroes stats ----
__global__ __launch_bounds__(256) void prep_pts(const float* __restrict__ x,
                                                float4* __restrict__ pts,
                                                double* __restrict__ stats) {
    if (blockIdx.x == 0 && threadIdx.x < 27) stats[threadIdx.x] = 0.0;
    int t = blockIdx.x * 256 + threadIdx.x;   // 0..32767
    int b = t >> 12;
    int n = t & (NPTS - 1);
    const float* xb = x + (size_t)b * CIN * NPTS;
    float x0 = xb[n];
    float x1 = xb[NPTS + n];
    float x2 = xb[2 * NPTS + n];
    pts[t] = make_float4(x0, x1, x2, x0 * x0 + x1 * x1 + x2 * x2);
}

// ---- Kernel A1: per-segment exact top-10 ----
// Pass A: branchless min/max chain keeps the 10 largest d' (values only, exact f32).
// Pass B: rescan, buffer (d,m) with d >= 10th value into LDS (~10/lane).
// Drain: strict-> insertion (R1 semantics) over the buffered candidates in index order.
__global__ __launch_bounds__(256) void knn_part(const float4* __restrict__ pts,
                                                int* __restrict__ part) {
    __shared__ float sd[CAP * 256];
    __shared__ int   sm[CAP * 256];
    int b = blockIdx.y;
    int s = blockIdx.z;
    int n = blockIdx.x * 256 + threadIdx.x;
    const float4* p = pts + (size_t)b * NPTS;   // wave-uniform base -> scalar loads
    float4 qp = p[n];

    float vals[K_NN];
#pragma unroll
    for (int j = 0; j < K_NN; j++) vals[j] = -FLT_MAX;

    int m0 = s * SEGLEN;
    // ---- pass A: values-only branchless chain (24 VALU / candidate) ----
#pragma unroll 8
    for (int mm = 0; mm < SEGLEN; mm++) {
        float4 c = p[m0 + mm];
        float t = distp(qp, c);
#pragma unroll
        for (int j = 0; j < K_NN; j++) {
            float hi = fmaxf(vals[j], t);
            t = fminf(vals[j], t);
            vals[j] = hi;
        }
    }
    float v10 = vals[K_NN - 1];   // exact 10th-largest d' of this segment

    // ---- pass B: collect survivors (d >= v10) with their indices ----
    int cnt = 0;
#pragma unroll 8
    for (int mm = 0; mm < SEGLEN; mm++) {
        float4 c = p[m0 + mm];
        float d = distp(qp, c);
        if (d >= v10 && cnt < CAP) {
            sd[cnt * 256 + threadIdx.x] = d;
            sm[cnt * 256 + threadIdx.x] = m0 + mm;
            cnt++;
        }
    }

    // ---- drain: strict-> sorted insert over <=CAP survivors, index order ----
    float fv[K_NN];
    int fi[K_NN];
#pragma unroll
    for (int j = 0; j < K_NN; j++) { fv[j] = -FLT_MAX; fi[j] = 0; }
    for (int j = 0; j < CAP; j++) {
        if (j < cnt) {
            float d = sd[j * 256 + threadIdx.x];
            int m = sm[j * 256 + threadIdx.x];
            if (d > fv[K_NN - 1]) {
                fv[K_NN - 1] = d;
                fi[K_NN - 1] = m;
#pragma unroll
                for (int t2 = K_NN - 1; t2 > 0; t2--) {
                    if (fv[t2] > fv[t2 - 1]) {
                        float tv = fv[t2]; fv[t2] = fv[t2 - 1]; fv[t2 - 1] = tv;
                        int ti = fi[t2]; fi[t2] = fi[t2 - 1]; fi[t2 - 1] = ti;
                    }
                }
            }
        }
    }

    int* o = part + (((size_t)s * BATCH + b) * K_NN) * NPTS + n;
#pragma unroll
    for (int j = 0; j < K_NN; j++) o[(size_t)j * NPTS] = fi[j];
}

// ---- Kernel A2: merge 8 segment lists -> global top-10 (re-evaluates 80 cands) ----
__global__ __launch_bounds__(256) void merge_kernel(const float4* __restrict__ pts,
                                                    const int* __restrict__ part,
                                                    int* __restrict__ idxo) {
    int b = blockIdx.y;
    int n = blockIdx.x * 256 + threadIdx.x;
    const float4* p = pts + (size_t)b * NPTS;
    float4 qp = p[n];

    float vals[K_NN];
    int inds[K_NN];
#pragma unroll
    for (int j = 0; j < K_NN; j++) { vals[j] = -FLT_MAX; inds[j] = 0; }

#pragma unroll
    for (int s = 0; s < NSEG; s++) {
        const int* pp = part + (((size_t)s * BATCH + b) * K_NN) * NPTS + n;
#pragma unroll
        for (int j = 0; j < K_NN; j++) {
            int m = pp[(size_t)j * NPTS];
            float4 c = p[m];                     // divergent but L1/L2-resident (512 KB)
            float d = distp(qp, c);
            if (d > vals[K_NN - 1]) {
                vals[K_NN - 1] = d;
                inds[K_NN - 1] = m;
#pragma unroll
                for (int t = K_NN - 1; t > 0; t--) {
                    if (vals[t] > vals[t - 1]) {
                        float tv = vals[t]; vals[t] = vals[t - 1]; vals[t - 1] = tv;
                        int ti = inds[t]; inds[t] = inds[t - 1]; inds[t - 1] = ti;
                    }
                }
            }
        }
    }

    // plane layout [b][j][n] : coalesced write, coalesced read in feat
    int* o = idxo + (size_t)b * K_NN * NPTS + n;
#pragma unroll
    for (int j = 0; j < K_NN; j++) o[(size_t)j * NPTS] = inds[j];
}

// ---- Kernel B: gather + center + q[b,o,n] = max_k (W feat) + moment stats ----
__global__ __launch_bounds__(256) void feat_kernel(const float4* __restrict__ pts,
                                                   const float* __restrict__ x,
                                                   const float* __restrict__ W,
                                                   const int* __restrict__ idx,
                                                   float* __restrict__ q,
                                                   double* __restrict__ stats) {
    __shared__ float sW[COUT * CIN];
    __shared__ float sred[4][27];
    for (int i = threadIdx.x; i < COUT * CIN; i += 256) sW[i] = W[i];
    __syncthreads();

    int b = blockIdx.y;
    int n = blockIdx.x * 256 + threadIdx.x;
    const float* xb = x + (size_t)b * CIN * NPTS;
    const float4* p = pts + (size_t)b * NPTS;

    int nb[K_NN];
#pragma unroll
    for (int k = 0; k < K_NN; k++) nb[k] = idx[((size_t)b * K_NN + k) * NPTS + n];

    float f[CIN][K_NN];
#pragma unroll
    for (int k = 0; k < K_NN; k++) {
        float4 c = p[nb[k]];                    // xyz in one 16B gather
        f[0][k] = c.x; f[1][k] = c.y; f[2][k] = c.z;
    }
#pragma unroll
    for (int c = 3; c < CIN; c++)
#pragma unroll
        for (int k = 0; k < K_NN; k++)
            f[c][k] = xb[c * NPTS + nb[k]];

    // center xyz over k, scale by 10
#pragma unroll
    for (int c = 0; c < 3; c++) {
        float s = 0.f;
#pragma unroll
        for (int k = 0; k < K_NN; k++) s += f[c][k];
        float m = s / 10.0f;
#pragma unroll
        for (int k = 0; k < K_NN; k++) f[c][k] = (f[c][k] - m) * 10.0f;
    }

    // q[b,o,n] = max_k y (BN affine + leaky are monotone -> applied in reduce)
    float* qb = q + (size_t)b * COUT * NPTS + n;
#pragma unroll
    for (int o = 0; o < COUT; o++) {
        float w0 = sW[o * 6 + 0], w1 = sW[o * 6 + 1], w2 = sW[o * 6 + 2];
        float w3 = sW[o * 6 + 3], w4 = sW[o * 6 + 4], w5 = sW[o * 6 + 5];
        float mx = -FLT_MAX;
#pragma unroll
        for (int k = 0; k < K_NN; k++) {
            float y = w0 * f[0][k] + w1 * f[1][k] + w2 * f[2][k] +
                      w3 * f[3][k] + w4 * f[4][k] + w5 * f[5][k];
            mx = fmaxf(mx, y);
        }
        qb[(size_t)o * NPTS] = mx;
    }

    // moment stats: S1[6], S2[21]
    float s1[CIN];
#pragma unroll
    for (int c = 0; c < CIN; c++) {
        float s = 0.f;
#pragma unroll
        for (int k = 0; k < K_NN; k++) s += f[c][k];
        s1[c] = s;
    }
    float s2[21];
#pragma unroll
    for (int i = 0; i < 21; i++) s2[i] = 0.f;
#pragma unroll
    for (int k = 0; k < K_NN; k++) {
        int pp = 0;
#pragma unroll
        for (int c = 0; c < CIN; c++)
#pragma unroll
            for (int c2 = c; c2 < CIN; c2++) {
                s2[pp] += f[c][k] * f[c2][k];
                pp++;
            }
    }
#pragma unroll
    for (int c = 0; c < CIN; c++) s1[c] = wave_sum(s1[c]);
#pragma unroll
    for (int i = 0; i < 21; i++) s2[i] = wave_sum(s2[i]);

    int wv = threadIdx.x >> 6;
    int ln = threadIdx.x & 63;
    if (ln == 0) {
#pragma unroll
        for (int c = 0; c < CIN; c++) sred[wv][c] = s1[c];
#pragma unroll
        for (int i = 0; i < 21; i++) sred[wv][6 + i] = s2[i];
    }
    __syncthreads();
    if (threadIdx.x < 27) {
        float t = sred[0][threadIdx.x] + sred[1][threadIdx.x] +
                  sred[2][threadIdx.x] + sred[3][threadIdx.x];
        atomicAdd(&stats[threadIdx.x], (double)t);
    }
}

// ---- Kernel B2: fold moments through W -> per-channel scale/shift ----
__global__ void stats_kernel(const double* __restrict__ stats,
                             const float* __restrict__ W,
                             const float* __restrict__ gamma,
                             const float* __restrict__ beta,
                             float* __restrict__ ss) {
    int o = threadIdx.x;  // 64 threads
    const double minv = 1.0 / (double)((size_t)BATCH * NPTS * K_NN);
    double w[CIN];
#pragma unroll
    for (int c = 0; c < CIN; c++) w[c] = (double)W[o * CIN + c];
    double mu = 0.0;
#pragma unroll
    for (int c = 0; c < CIN; c++) mu += w[c] * stats[c];
    mu *= minv;
    double ey2 = 0.0;
    int p = 6;
#pragma unroll
    for (int c = 0; c < CIN; c++)
#pragma unroll
        for (int c2 = c; c2 < CIN; c2++) {
            double v = w[c] * w[c2] * stats[p];
            ey2 += (c2 == c) ? v : 2.0 * v;
            p++;
        }
    ey2 *= minv;
    double var = ey2 - mu * mu;
    float scale = gamma[o] * rsqrtf((float)var + BN_EPS);
    float shift = beta[o] - (float)mu * scale;
    ss[o] = scale;
    ss[COUT + o] = shift;
}

// ---- Kernel C: z = leaky(scale*q+shift); reduce max & mean over n ----
__global__ __launch_bounds__(256) void reduce_kernel(const float* __restrict__ q,
                                                     const float* __restrict__ ss,
                                                     float* __restrict__ out) {
    int o = blockIdx.x;
    int b = blockIdx.y;
    const float* qp = q + ((size_t)b * COUT + o) * NPTS;
    float scale = ss[o], shift = ss[COUT + o];
    float mx = -FLT_MAX, sm = 0.f;
    for (int i = threadIdx.x; i < NPTS; i += 256) {
        float z = scale * qp[i] + shift;
        z = (z >= 0.f) ? z : NEG_SLOPE * z;
        mx = fmaxf(mx, z);
        sm += z;
    }
    mx = wave_max(mx);
    sm = wave_sum(sm);
    __shared__ float smx[4], ssm[4];
    int wv = threadIdx.x >> 6;
    int ln = threadIdx.x & 63;
    if (ln == 0) { smx[wv] = mx; ssm[wv] = sm; }
    __syncthreads();
    if (threadIdx.x == 0) {
        float m = fmaxf(fmaxf(smx[0], smx[1]), fmaxf(smx[2], smx[3]));
        float s = ssm[0] + ssm[1] + ssm[2] + ssm[3];
        out[b * 2 * COUT + o] = m;
        out[b * 2 * COUT + COUT + o] = s * (1.0f / (float)NPTS);
    }
}

extern "C" void kernel_launch(void* const* d_in, const int* in_sizes, int n_in,
                              void* d_out, int out_size, void* d_ws, size_t ws_size,
                              hipStream_t stream) {
    const float* x     = (const float*)d_in[0];
    const float* W     = (const float*)d_in[1];
    const float* gamma = (const float*)d_in[2];
    const float* beta  = (const float*)d_in[3];
    float* out = (float*)d_out;

    char* ws = (char*)d_ws;
    int*    idx   = (int*)(ws + OFF_IDX);
    float4* pts   = (float4*)(ws + OFF_PTS);
    int*    part  = (int*)(ws + OFF_Q);     // aliases q region (consumed before q written)
    float*  q     = (float*)(ws + OFF_Q);
    double* stats = (double*)(ws + OFF_ST);
    float*  ss    = (float*)(ws + OFF_SS);

    prep_pts<<<BATCH * NPTS / 256, 256, 0, stream>>>(x, pts, stats);
    knn_part<<<dim3(NPTS / 256, BATCH, NSEG), 256, 0, stream>>>(pts, part);
    merge_kernel<<<dim3(NPTS / 256, BATCH), 256, 0, stream>>>(pts, part, idx);
    feat_kernel<<<dim3(NPTS / 256, BATCH), 256, 0, stream>>>(pts, x, W, idx, q, stats);
    stats_kernel<<<1, COUT, 0, stream>>>(stats, W, gamma, beta, ss);
    reduce_kernel<<<dim3(COUT, BATCH), 256, 0, stream>>>(q, ss, out);
}

// Round 4
// 197.492 us; speedup vs baseline: 3.9142x; 1.3298x over previous
//
#include <hip/hip_runtime.h>
#include <float.h>

#define K_NN 10
#define BATCH 8
#define CIN 6
#define NPTS 4096
#define COUT 64
#define NSEG 8
#define SEGLEN (NPTS / NSEG)   // 512
#define CHUNK 16
#define NCHUNK (SEGLEN / CHUNK) // 32
#define CAP 32                  // survivor buffer (E[survivors]~12; exact fallback if overflow)
#define NEG_SLOPE 0.2f
#define BN_EPS 1e-5f

// ---- workspace layout (bytes) ----
// part[] aliases q[]: part is fully consumed by merge_kernel before feat_kernel writes q.
static constexpr size_t OFF_IDX = 0;                                                   // int[8*10*4096]  (plane layout [b][j][n])
static constexpr size_t OFF_PTS = OFF_IDX + (size_t)BATCH * K_NN * NPTS * sizeof(int); // float4[8*4096]
static constexpr size_t OFF_Q   = OFF_PTS + (size_t)BATCH * NPTS * sizeof(float4);     // alias: q / part
static constexpr size_t SZ_Q    = (size_t)NSEG * BATCH * NPTS * K_NN * sizeof(int);    // 10.49 MB
static constexpr size_t OFF_ST  = OFF_Q + SZ_Q;                                        // double[27]
static constexpr size_t OFF_SS  = OFF_ST + 32 * sizeof(double);                        // float[128]

__device__ __forceinline__ float wave_sum(float v) {
#pragma unroll
    for (int m = 32; m >= 1; m >>= 1) v += __shfl_xor(v, m, 64);
    return v;
}
__device__ __forceinline__ float wave_max(float v) {
#pragma unroll
    for (int m = 32; m >= 1; m >>= 1) v = fmaxf(v, __shfl_xor(v, m, 64));
    return v;
}

// d' = 2*inner - ||c||^2  (drops per-query-constant ||q||^2: monotone shift, used
// consistently in knn_part AND merge_kernel). 4 VALU.
__device__ __forceinline__ float distp(float4 qp, float4 c) {
    return fmaf(2.0f, fmaf(qp.z, c.z, fmaf(qp.y, c.y, qp.x * c.x)), -c.w);
}

// ---- Kernel P: pack (x,y,z,||p||^2) per point; block 0 zeroes stats ----
__global__ __launch_bounds__(256) void prep_pts(const float* __restrict__ x,
                                                float4* __restrict__ pts,
                                                double* __restrict__ stats) {
    if (blockIdx.x == 0 && threadIdx.x < 27) stats[threadIdx.x] = 0.0;
    int t = blockIdx.x * 256 + threadIdx.x;   // 0..32767
    int b = t >> 12;
    int n = t & (NPTS - 1);
    const float* xb = x + (size_t)b * CIN * NPTS;
    float x0 = xb[n];
    float x1 = xb[NPTS + n];
    float x2 = xb[2 * NPTS + n];
    pts[t] = make_float4(x0, x1, x2, x0 * x0 + x1 * x1 + x2 * x2);
}

// ---- Kernel A1: per-segment exact top-10, chunk-max threshold scheme ----
// Phase 1: chunk maxima (chunks of 16) pushed through a 10-deep branchless chain
//          -> t = 10th-largest chunk max. Provably t <= v10 (10 distinct chunks
//          each contain >=1 element >= t).
// Phase 2: collect indices of all d >= t into per-lane LDS u16 slots (E~12).
//          Branch-free: unconditional store to slot min(cnt,CAP-1), conditional cnt++.
// Drain:   strict-> insertion (R1 semantics) over survivors in candidate order.
// Fallback: cnt > CAP (P~1e-10/lane) -> exact branchy rescan of the segment.
__global__ __launch_bounds__(256) void knn_part(const float4* __restrict__ pts,
                                                int* __restrict__ part) {
    __shared__ unsigned short ssm[CAP * 256];
    int b = blockIdx.y;
    int s = blockIdx.z;
    int n = blockIdx.x * 256 + threadIdx.x;
    const float4* p = pts + (size_t)b * NPTS;   // wave-uniform base -> scalar loads
    float4 qp = p[n];

    int m0 = s * SEGLEN;

    // ---- phase 1: threshold from chunk maxima ----
    float vals[K_NN];
#pragma unroll
    for (int j = 0; j < K_NN; j++) vals[j] = -FLT_MAX;

    for (int ch = 0; ch < NCHUNK; ch++) {
        float cmax = -FLT_MAX;
#pragma unroll
        for (int u = 0; u < CHUNK; u++) {
            float4 c = p[m0 + ch * CHUNK + u];
            cmax = fmaxf(cmax, distp(qp, c));
        }
        float t = cmax;
#pragma unroll
        for (int j = 0; j < K_NN; j++) {
            float hi = fmaxf(vals[j], t);
            t = fminf(vals[j], t);
            vals[j] = hi;
        }
    }
    float thr = vals[K_NN - 1];   // 10th-largest chunk max  (<= exact v10)

    // ---- phase 2: collect survivors (d >= thr), branch-free ----
    int cnt = 0;
#pragma unroll 8
    for (int mm = 0; mm < SEGLEN; mm++) {
        float4 c = p[m0 + mm];
        float d = distp(qp, c);
        int slot = min(cnt, CAP - 1);
        ssm[slot * 256 + threadIdx.x] = (unsigned short)(m0 + mm);
        cnt += (d >= thr) ? 1 : 0;
    }

    // ---- drain: exact strict-> insert over survivors (candidate order) ----
    float fv[K_NN];
    int fi[K_NN];
#pragma unroll
    for (int j = 0; j < K_NN; j++) { fv[j] = -FLT_MAX; fi[j] = 0; }

    if (cnt <= CAP) {
        for (int j = 0; j < cnt; j++) {
            int m = ssm[j * 256 + threadIdx.x];
            float4 c = p[m];                    // L1-hot (segment = 8 KB)
            float d = distp(qp, c);
            if (d > fv[K_NN - 1]) {
                fv[K_NN - 1] = d;
                fi[K_NN - 1] = m;
#pragma unroll
                for (int t2 = K_NN - 1; t2 > 0; t2--) {
                    if (fv[t2] > fv[t2 - 1]) {
                        float tv = fv[t2]; fv[t2] = fv[t2 - 1]; fv[t2 - 1] = tv;
                        int ti = fi[t2]; fi[t2] = fi[t2 - 1]; fi[t2 - 1] = ti;
                    }
                }
            }
        }
    } else {
        // exact fallback (essentially never taken; guarantees correctness)
        for (int mm = 0; mm < SEGLEN; mm++) {
            int m = m0 + mm;
            float4 c = p[m];
            float d = distp(qp, c);
            if (d > fv[K_NN - 1]) {
                fv[K_NN - 1] = d;
                fi[K_NN - 1] = m;
#pragma unroll
                for (int t2 = K_NN - 1; t2 > 0; t2--) {
                    if (fv[t2] > fv[t2 - 1]) {
                        float tv = fv[t2]; fv[t2] = fv[t2 - 1]; fv[t2 - 1] = tv;
                        int ti = fi[t2]; fi[t2] = fi[t2 - 1]; fi[t2 - 1] = ti;
                    }
                }
            }
        }
    }

    int* o = part + (((size_t)s * BATCH + b) * K_NN) * NPTS + n;
#pragma unroll
    for (int j = 0; j < K_NN; j++) o[(size_t)j * NPTS] = fi[j];
}

// ---- Kernel A2: merge 8 segment lists -> global top-10 (re-evaluates 80 cands) ----
__global__ __launch_bounds__(256) void merge_kernel(const float4* __restrict__ pts,
                                                    const int* __restrict__ part,
                                                    int* __restrict__ idxo) {
    int b = blockIdx.y;
    int n = blockIdx.x * 256 + threadIdx.x;
    const float4* p = pts + (size_t)b * NPTS;
    float4 qp = p[n];

    float vals[K_NN];
    int inds[K_NN];
#pragma unroll
    for (int j = 0; j < K_NN; j++) { vals[j] = -FLT_MAX; inds[j] = 0; }

#pragma unroll
    for (int s = 0; s < NSEG; s++) {
        const int* pp = part + (((size_t)s * BATCH + b) * K_NN) * NPTS + n;
#pragma unroll
        for (int j = 0; j < K_NN; j++) {
            int m = pp[(size_t)j * NPTS];
            float4 c = p[m];                     // divergent but L2-resident (512 KB)
            float d = distp(qp, c);
            if (d > vals[K_NN - 1]) {
                vals[K_NN - 1] = d;
                inds[K_NN - 1] = m;
#pragma unroll
                for (int t = K_NN - 1; t > 0; t--) {
                    if (vals[t] > vals[t - 1]) {
                        float tv = vals[t]; vals[t] = vals[t - 1]; vals[t - 1] = tv;
                        int ti = inds[t]; inds[t] = inds[t - 1]; inds[t - 1] = ti;
                    }
                }
            }
        }
    }

    // plane layout [b][j][n] : coalesced write, coalesced read in feat
    int* o = idxo + (size_t)b * K_NN * NPTS + n;
#pragma unroll
    for (int j = 0; j < K_NN; j++) o[(size_t)j * NPTS] = inds[j];
}

// ---- Kernel B: gather + center + q[b,o,n] = max_k (W feat) + moment stats ----
__global__ __launch_bounds__(256) void feat_kernel(const float4* __restrict__ pts,
                                                   const float* __restrict__ x,
                                                   const float* __restrict__ W,
                                                   const int* __restrict__ idx,
                                                   float* __restrict__ q,
                                                   double* __restrict__ stats) {
    __shared__ float sW[COUT * CIN];
    __shared__ float sred[4][27];
    for (int i = threadIdx.x; i < COUT * CIN; i += 256) sW[i] = W[i];
    __syncthreads();

    int b = blockIdx.y;
    int n = blockIdx.x * 256 + threadIdx.x;
    const float* xb = x + (size_t)b * CIN * NPTS;
    const float4* p = pts + (size_t)b * NPTS;

    int nb[K_NN];
#pragma unroll
    for (int k = 0; k < K_NN; k++) nb[k] = idx[((size_t)b * K_NN + k) * NPTS + n];

    float f[CIN][K_NN];
#pragma unroll
    for (int k = 0; k < K_NN; k++) {
        float4 c = p[nb[k]];                    // xyz in one 16B gather
        f[0][k] = c.x; f[1][k] = c.y; f[2][k] = c.z;
    }
#pragma unroll
    for (int c = 3; c < CIN; c++)
#pragma unroll
        for (int k = 0; k < K_NN; k++)
            f[c][k] = xb[c * NPTS + nb[k]];

    // center xyz over k, scale by 10
#pragma unroll
    for (int c = 0; c < 3; c++) {
        float s = 0.f;
#pragma unroll
        for (int k = 0; k < K_NN; k++) s += f[c][k];
        float m = s / 10.0f;
#pragma unroll
        for (int k = 0; k < K_NN; k++) f[c][k] = (f[c][k] - m) * 10.0f;
    }

    // q[b,o,n] = max_k y (BN affine + leaky are monotone -> applied in reduce)
    float* qb = q + (size_t)b * COUT * NPTS + n;
#pragma unroll
    for (int o = 0; o < COUT; o++) {
        float w0 = sW[o * 6 + 0], w1 = sW[o * 6 + 1], w2 = sW[o * 6 + 2];
        float w3 = sW[o * 6 + 3], w4 = sW[o * 6 + 4], w5 = sW[o * 6 + 5];
        float mx = -FLT_MAX;
#pragma unroll
        for (int k = 0; k < K_NN; k++) {
            float y = w0 * f[0][k] + w1 * f[1][k] + w2 * f[2][k] +
                      w3 * f[3][k] + w4 * f[4][k] + w5 * f[5][k];
            mx = fmaxf(mx, y);
        }
        qb[(size_t)o * NPTS] = mx;
    }

    // moment stats: S1[6], S2[21]
    float s1[CIN];
#pragma unroll
    for (int c = 0; c < CIN; c++) {
        float s = 0.f;
#pragma unroll
        for (int k = 0; k < K_NN; k++) s += f[c][k];
        s1[c] = s;
    }
    float s2[21];
#pragma unroll
    for (int i = 0; i < 21; i++) s2[i] = 0.f;
#pragma unroll
    for (int k = 0; k < K_NN; k++) {
        int pp = 0;
#pragma unroll
        for (int c = 0; c < CIN; c++)
#pragma unroll
            for (int c2 = c; c2 < CIN; c2++) {
                s2[pp] += f[c][k] * f[c2][k];
                pp++;
            }
    }
#pragma unroll
    for (int c = 0; c < CIN; c++) s1[c] = wave_sum(s1[c]);
#pragma unroll
    for (int i = 0; i < 21; i++) s2[i] = wave_sum(s2[i]);

    int wv = threadIdx.x >> 6;
    int ln = threadIdx.x & 63;
    if (ln == 0) {
#pragma unroll
        for (int c = 0; c < CIN; c++) sred[wv][c] = s1[c];
#pragma unroll
        for (int i = 0; i < 21; i++) sred[wv][6 + i] = s2[i];
    }
    __syncthreads();
    if (threadIdx.x < 27) {
        float t = sred[0][threadIdx.x] + sred[1][threadIdx.x] +
                  sred[2][threadIdx.x] + sred[3][threadIdx.x];
        atomicAdd(&stats[threadIdx.x], (double)t);
    }
}

// ---- Kernel B2: fold moments through W -> per-channel scale/shift ----
__global__ void stats_kernel(const double* __restrict__ stats,
                             const float* __restrict__ W,
                             const float* __restrict__ gamma,
                             const float* __restrict__ beta,
                             float* __restrict__ ss) {
    int o = threadIdx.x;  // 64 threads
    const double minv = 1.0 / (double)((size_t)BATCH * NPTS * K_NN);
    double w[CIN];
#pragma unroll
    for (int c = 0; c < CIN; c++) w[c] = (double)W[o * CIN + c];
    double mu = 0.0;
#pragma unroll
    for (int c = 0; c < CIN; c++) mu += w[c] * stats[c];
    mu *= minv;
    double ey2 = 0.0;
    int p = 6;
#pragma unroll
    for (int c = 0; c < CIN; c++)
#pragma unroll
        for (int c2 = c; c2 < CIN; c2++) {
            double v = w[c] * w[c2] * stats[p];
            ey2 += (c2 == c) ? v : 2.0 * v;
            p++;
        }
    ey2 *= minv;
    double var = ey2 - mu * mu;
    float scale = gamma[o] * rsqrtf((float)var + BN_EPS);
    float shift = beta[o] - (float)mu * scale;
    ss[o] = scale;
    ss[COUT + o] = shift;
}

// ---- Kernel C: z = leaky(scale*q+shift); reduce max & mean over n ----
__global__ __launch_bounds__(256) void reduce_kernel(const float* __restrict__ q,
                                                     const float* __restrict__ ss,
                                                     float* __restrict__ out) {
    int o = blockIdx.x;
    int b = blockIdx.y;
    const float* qp = q + ((size_t)b * COUT + o) * NPTS;
    float scale = ss[o], shift = ss[COUT + o];
    float mx = -FLT_MAX, sm = 0.f;
    for (int i = threadIdx.x; i < NPTS; i += 256) {
        float z = scale * qp[i] + shift;
        z = (z >= 0.f) ? z : NEG_SLOPE * z;
        mx = fmaxf(mx, z);
        sm += z;
    }
    mx = wave_max(mx);
    sm = wave_sum(sm);
    __shared__ float smx[4], ssm2[4];
    int wv = threadIdx.x >> 6;
    int ln = threadIdx.x & 63;
    if (ln == 0) { smx[wv] = mx; ssm2[wv] = sm; }
    __syncthreads();
    if (threadIdx.x == 0) {
        float m = fmaxf(fmaxf(smx[0], smx[1]), fmaxf(smx[2], smx[3]));
        float s = ssm2[0] + ssm2[1] + ssm2[2] + ssm2[3];
        out[b * 2 * COUT + o] = m;
        out[b * 2 * COUT + COUT + o] = s * (1.0f / (float)NPTS);
    }
}

extern "C" void kernel_launch(void* const* d_in, const int* in_sizes, int n_in,
                              void* d_out, int out_size, void* d_ws, size_t ws_size,
                              hipStream_t stream) {
    const float* x     = (const float*)d_in[0];
    const float* W     = (const float*)d_in[1];
    const float* gamma = (const float*)d_in[2];
    const float* beta  = (const float*)d_in[3];
    float* out = (float*)d_out;

    char* ws = (char*)d_ws;
    int*    idx   = (int*)(ws + OFF_IDX);
    float4* pts   = (float4*)(ws + OFF_PTS);
    int*    part  = (int*)(ws + OFF_Q);     // aliases q region (consumed before q written)
    float*  q     = (float*)(ws + OFF_Q);
    double* stats = (double*)(ws + OFF_ST);
    float*  ss    = (float*)(ws + OFF_SS);

    prep_pts<<<BATCH * NPTS / 256, 256, 0, stream>>>(x, pts, stats);
    knn_part<<<dim3(NPTS / 256, BATCH, NSEG), 256, 0, stream>>>(pts, part);
    merge_kernel<<<dim3(NPTS / 256, BATCH), 256, 0, stream>>>(pts, part, idx);
    feat_kernel<<<dim3(NPTS / 256, BATCH), 256, 0, stream>>>(pts, x, W, idx, q, stats);
    stats_kernel<<<1, COUT, 0, stream>>>(stats, W, gamma, beta, ss);
    reduce_kernel<<<dim3(COUT, BATCH), 256, 0, stream>>>(q, ss, out);
}